// Round 6
// baseline (331.140 us; speedup 1.0000x reference)
//
#include <hip/hip_runtime.h>
#include <stdint.h>

// T-structure as a signed permutation: for each (k,p) there is exactly one q
// with sign s such that T[k,p,q] = s. Transcribed from _TERMS.
__constant__ signed char QTAB[64] = {
    0,1,2,3,4,5,6,7,
    1,0,4,5,2,3,7,6,
    2,4,0,6,1,7,3,5,
    3,5,6,0,7,1,2,4,
    4,2,1,7,0,6,5,3,
    5,3,7,1,6,0,4,2,
    6,7,3,2,5,4,0,1,
    7,6,5,4,3,2,1,0};
__constant__ signed char SGN[64] = {
    1, 1, 1, 1,-1,-1,-1,-1,
    1, 1,-1, 1, 1,-1,-1,-1,
    1, 1, 1,-1,-1, 1, 1,-1,
    1,-1, 1, 1,-1,-1,-1, 1,
    1, 1,-1, 1, 1,-1, 1,-1,
    1,-1, 1, 1, 1, 1,-1,-1,
    1,-1,-1, 1,-1, 1, 1, 1,
    1, 1,-1, 1, 1,-1, 1, 1};

// W2[iq][m] such that out[b][m] = sum_iq x[b][iq] * W2[iq][m]  (m = o*8+k,
// iq = i*8+q). Each entry written exactly once (QTAB rows are permutations).
__global__ void clifford_prep(const float* __restrict__ weight,
                              float* __restrict__ W2) {
    int t = threadIdx.x;
    for (int e = t; e < 4096; e += 256) {
        int o = e >> 9, i = (e >> 6) & 7, k = (e >> 3) & 7, p = e & 7;
        int q = (int)QTAB[k * 8 + p];
        float s = (float)SGN[k * 8 + p];
        W2[((i * 8 + q) * 64) + (o * 8 + k)] = s * weight[(o * 8 + i) * 8 + p];
    }
}

typedef __attribute__((address_space(1))) const float gfloat;
typedef __attribute__((address_space(3))) float sfloat;

#define SBAR __builtin_amdgcn_sched_barrier(0)
#define WAITVM(N)                                        \
    asm volatile("s_waitcnt vmcnt(" #N ")" ::: "memory"); \
    SBAR
#define WLGKM                                            \
    asm volatile("s_waitcnt lgkmcnt(0)" ::: "memory");   \
    SBAR

// Stage one 8-row chunk (8 x 64 f32 = 2 KB) linearly into LDS buffer BUF.
// Two 1-KB global_load_lds instrs; global src per-lane, LDS dest uniform
// (HW scatters lane*16). Perfectly coalesced, no swizzle needed: all LDS
// reads of this data are wave-uniform broadcasts (conflict-free by nature).
#define ISSUE_CHUNK(CI, BUF)                                                 \
    {                                                                        \
        const float* src_ = x + (size_t)(CI) * 512 + (l << 2);               \
        __builtin_amdgcn_global_load_lds((gfloat*)(src_),                    \
                                         (sfloat*)(smw + (BUF) * 512), 16,   \
                                         0, 0);                              \
        __builtin_amdgcn_global_load_lds(                                    \
            (gfloat*)(src_ + 256), (sfloat*)(smw + (BUF) * 512 + 256), 16,   \
            0, 0);                                                           \
    }

// Compute + store one chunk: lane l owns output column m=l. Two groups of
// 4 rows; per group 4 independent FMA chains (latency-covered), x values
// come in as broadcast float4 LDS reads, W from per-lane registers.
// Stores: lane l writes out[row][l] -> 256 B contiguous per instruction.
#define DO_CHUNK(CI, BUF)                                                    \
    {                                                                        \
        float* ot_ = out + (size_t)(CI) * 512 + l;                           \
        _Pragma("unroll") for (int g_ = 0; g_ < 2; ++g_) {                   \
            float a0 = bv, a1 = bv, a2 = bv, a3 = bv;                        \
            const float* bp_ = smw + (BUF) * 512 + g_ * 256;                 \
            _Pragma("unroll") for (int j_ = 0; j_ < 16; ++j_) {              \
                float4 x0 = *(const float4*)(bp_ + 4 * j_);                  \
                float4 x1 = *(const float4*)(bp_ + 64 + 4 * j_);             \
                float4 x2 = *(const float4*)(bp_ + 128 + 4 * j_);            \
                float4 x3 = *(const float4*)(bp_ + 192 + 4 * j_);            \
                a0 = fmaf(x0.x, Wv[4 * j_ + 0], a0);                         \
                a1 = fmaf(x1.x, Wv[4 * j_ + 0], a1);                         \
                a2 = fmaf(x2.x, Wv[4 * j_ + 0], a2);                         \
                a3 = fmaf(x3.x, Wv[4 * j_ + 0], a3);                         \
                a0 = fmaf(x0.y, Wv[4 * j_ + 1], a0);                         \
                a1 = fmaf(x1.y, Wv[4 * j_ + 1], a1);                         \
                a2 = fmaf(x2.y, Wv[4 * j_ + 1], a2);                         \
                a3 = fmaf(x3.y, Wv[4 * j_ + 1], a3);                         \
                a0 = fmaf(x0.z, Wv[4 * j_ + 2], a0);                         \
                a1 = fmaf(x1.z, Wv[4 * j_ + 2], a1);                         \
                a2 = fmaf(x2.z, Wv[4 * j_ + 2], a2);                         \
                a3 = fmaf(x3.z, Wv[4 * j_ + 2], a3);                         \
                a0 = fmaf(x0.w, Wv[4 * j_ + 3], a0);                         \
                a1 = fmaf(x1.w, Wv[4 * j_ + 3], a1);                         \
                a2 = fmaf(x2.w, Wv[4 * j_ + 3], a2);                         \
                a3 = fmaf(x3.w, Wv[4 * j_ + 3], a3);                         \
            }                                                                \
            ot_[(g_ * 4 + 0) * 64] = a0;                                     \
            ot_[(g_ * 4 + 1) * 64] = a1;                                     \
            ot_[(g_ * 4 + 2) * 64] = a2;                                     \
            ot_[(g_ * 4 + 3) * 64] = a3;                                     \
        }                                                                    \
    }

// lane = output index m: W column in 64 VGPRs (loaded once), x broadcast
// from LDS, coalesced stores, no transposes. 4 KB LDS/wave -> occupancy
// VGPR-capped (~5 waves/SIMD), counted-vmcnt 2-chunk lookahead.
__global__ __launch_bounds__(256) void clifford_main(
    const float* __restrict__ x, const float* __restrict__ W,
    const float* __restrict__ bias, float* __restrict__ out, int nB) {
    __shared__ __align__(16) float smem[4][1024];  // 2 buffers x 512 f32/wave
    const int l = threadIdx.x & 63;
    const int wv = threadIdx.x >> 6;
    float* smw = smem[wv];
    const int nC = nB >> 3;  // 8-row chunks
    const long long nW = (long long)gridDim.x * 4;
    const long long w = (long long)blockIdx.x * 4 + wv;
    const int cpw = (int)(nC / nW);
    const long long rem = nC - (long long)cpw * nW;

    float Wv[64];
#pragma unroll
    for (int iq = 0; iq < 64; ++iq) Wv[iq] = W[iq * 64 + l];
    const float bv = bias[l];

    const long long c0 = w * cpw;
    if (cpw >= 3) {
        ISSUE_CHUNK(c0, 0);
        ISSUE_CHUNK(c0 + 1, 1);
        WAITVM(2);  // chunk c0 staged (also drains Wv/bias loads)
        for (int i = 0; i < cpw - 2; ++i) {
            const long long c = c0 + i;
            const int buf = i & 1;
            if (buf == 0) {
                DO_CHUNK(c, 0);
                WLGKM;  // chunk's ds_reads consumed -> safe to overwrite
                ISSUE_CHUNK(c + 2, 0);
            } else {
                DO_CHUNK(c, 1);
                WLGKM;
                ISSUE_CHUNK(c + 2, 1);
            }
            // queue: [L(c+1):2, S(c):8, L(c+2):2] -> retire exactly L(c+1)
            WAITVM(10);
        }
        if (((cpw - 2) & 1) == 0) {
            DO_CHUNK(c0 + cpw - 2, 0);
        } else {
            DO_CHUNK(c0 + cpw - 2, 1);
        }
        // queue <= [S(prev):8, L(last):2, S(this):8] -> vmcnt(8) retires
        // everything through L(last)
        WAITVM(8);
        if (((cpw - 1) & 1) == 0) {
            DO_CHUNK(c0 + cpw - 1, 0);
        } else {
            DO_CHUNK(c0 + cpw - 1, 1);
        }
    } else {
        for (int i = 0; i < cpw; ++i) {
            ISSUE_CHUNK(c0 + i, 0);
            WAITVM(0);
            DO_CHUNK(c0 + i, 0);
            WLGKM;
        }
    }
    if (w < rem) {  // leftover chunks (0 for the bench shape)
        const long long c = nW * cpw + w;
        WAITVM(0);
        ISSUE_CHUNK(c, 0);
        WAITVM(0);
        DO_CHUNK(c, 0);
    }
}

extern "C" void kernel_launch(void* const* d_in, const int* in_sizes, int n_in,
                              void* d_out, int out_size, void* d_ws,
                              size_t ws_size, hipStream_t stream) {
    const float* x = (const float*)d_in[0];
    const float* weight = (const float*)d_in[1];
    const float* bias = (const float*)d_in[2];
    float* out = (float*)d_out;
    float* W2 = (float*)d_ws;  // 4096 floats = 16 KB scratch

    int nB = in_sizes[0] / 64;  // 4096*512 batch elements

    hipLaunchKernelGGL(clifford_prep, dim3(1), dim3(256), 0, stream, weight,
                       W2);
    int nC = nB >> 3;
    int blocks = 2048;  // 8192 waves -> exactly 32 chunks/wave at nB=2^21
    if (blocks * 4 > nC) blocks = (nC + 3) / 4;
    if (blocks < 1) blocks = 1;
    hipLaunchKernelGGL(clifford_main, dim3(blocks), dim3(256), 0, stream, x,
                       W2, bias, out, nB);
}